// Round 4
// baseline (150.625 us; speedup 1.0000x reference)
//
#include <hip/hip_runtime.h>
#include <math.h>

#define NTH 256          // 4 waves per block
#define SPB 4            // samples per block (shared by all 4 waves)

__device__ __forceinline__ float waveSum(float v) {
#pragma unroll
  for (int off = 32; off; off >>= 1) v += __shfl_xor(v, off, 64);
  return v;
}

__device__ __forceinline__ float siluf(float x) { return x / (1.0f + expf(-x)); }

// Per-sample PL helper: given 5 selected exp-logits (uniform across wave), Z,
// each lane accumulates its share of the 120-permutation sum of
// prod_j 1/(Z - prefix). Lane p handles perms p and p+64.
__device__ __forceinline__ float permSum(const float se0, const float se1,
                                         const float se2, const float se3,
                                         const float se4, float Z, int lane) {
  float psum = 0.0f;
#pragma unroll
  for (int pp = 0; pp < 2; ++pp) {
    int p = lane + pp * 64;
    if (p < 120) {
      int rem = p;
      unsigned avail = 0x43210u;  // nibble i holds value i
      float c = 0.0f;
      float prod = Z;             // denominator for step 0
#pragma unroll
      for (int j = 0; j < 4; ++j) {
        const int fct = (j == 0) ? 24 : (j == 1) ? 6 : (j == 2) ? 2 : 1;
        int q = rem / fct; rem -= q * fct;
        int sh = q * 4;
        int dg = (avail >> sh) & 0xF;
        avail = (avail & ((1u << sh) - 1u)) | ((avail >> (sh + 4)) << sh);
        float ev = (dg == 0) ? se0 : (dg == 1) ? se1 : (dg == 2) ? se2
                 : (dg == 3) ? se3 : se4;
        c += ev;
        prod *= (Z - c);
      }
      psum += 1.0f / prod;
    }
  }
  return psum;
}

__global__ __launch_bounds__(NTH, 8)
void pcf_fused(const float* __restrict__ ua, const float* __restrict__ ub,
               const float* __restrict__ alog, const float* __restrict__ W1,
               const float* __restrict__ b1, const float* __restrict__ W2,
               const float* __restrict__ b2, const float* __restrict__ V1,
               const float* __restrict__ c1, const float* __restrict__ V2,
               const float* __restrict__ c2, const float* __restrict__ V3,
               const float* __restrict__ c3, float* __restrict__ out)
{
  // Block-shared activations for the 4 samples.
  __shared__ float sA[SPB * 256];   // h rows (s*128+j), later z1 (s*256+k)
  __shared__ float sB[SPB * 256];   // ctx (s*64+c),     later z2 (s*256+k)
  __shared__ float sP[4 * 256];     // per-wave partials for k-split reduces
  __shared__ int   sSelA[SPB * 5];
  __shared__ float sLpA[SPB];

  const int t    = threadIdx.x;
  const int lane = t & 63;
  const int wv   = t >> 6;
  const int bbase = blockIdx.x * SPB;

  //============ Phase A: alpha top-5 + PL (one sample per wave) ============
  {
    float la = alog[lane];
    float ea = expf(la);
    float Za = waveSum(ea);
    int b = bbase + wv;
    float u = ua[(size_t)b * 64 + lane];
    float g = -logf(-logf(fmaxf(u, 1e-10f)));
    float vcur = la + g;
    float sel_e[5]; int sel_i[5];
#pragma unroll
    for (int r = 0; r < 5; ++r) {
      float bv = vcur; int bi = lane;
#pragma unroll
      for (int off = 32; off; off >>= 1) {
        float ov = __shfl_xor(bv, off, 64);
        int   oi = __shfl_xor(bi, off, 64);
        if (ov > bv || (ov == bv && oi < bi)) { bv = ov; bi = oi; }
      }
      sel_i[r] = bi;                 // wave-uniform after butterfly
      sel_e[r] = __shfl(ea, bi, 64);
      if (lane == bi) vcur = -INFINITY;
    }
    float isSel = (vcur == -INFINITY) ? 1.0f : 0.0f;
    out[(size_t)b * 128 + lane] = isSel;                 // alpha config
    float sl = waveSum(isSel != 0.0f ? la : 0.0f);
    float S  = waveSum(permSum(sel_e[0], sel_e[1], sel_e[2], sel_e[3],
                               sel_e[4], Za, lane));
    if (lane == 0) {
      sLpA[wv] = sl + logf(S);
#pragma unroll
      for (int r = 0; r < 5; ++r) sSelA[wv * 5 + r] = sel_i[r];
    }
  }
  __syncthreads();

  //============ Phase H: h[s] = silu(b1 + sum of 5 W1 rows) ============
  {
    int s = wv;   // wave wv builds sample wv's h row (j = lane, lane+64)
    int i0 = sSelA[s * 5 + 0], i1 = sSelA[s * 5 + 1], i2 = sSelA[s * 5 + 2];
    int i3 = sSelA[s * 5 + 3], i4 = sSelA[s * 5 + 4];
#pragma unroll
    for (int jh = 0; jh < 2; ++jh) {
      int j = lane + jh * 64;
      float acc = b1[j] + W1[i0 * 128 + j] + W1[i1 * 128 + j]
                + W1[i2 * 128 + j] + W1[i3 * 128 + j] + W1[i4 * 128 + j];
      sA[s * 128 + j] = siluf(acc);
    }
  }
  __syncthreads();

  //============ GEMM1 partial: ctx = h @ W2 (K=128, k-split 4) ============
  {
    float acc[SPB] = {};
    const int kb = 32 * wv;
#pragma unroll 2
    for (int m = 0; m < 8; ++m) {       // 4 k per m
      int k0 = kb + 4 * m;
      float w0 = W2[(k0 + 0) * 64 + lane];
      float w1 = W2[(k0 + 1) * 64 + lane];
      float w2 = W2[(k0 + 2) * 64 + lane];
      float w3 = W2[(k0 + 3) * 64 + lane];
#pragma unroll
      for (int s = 0; s < SPB; ++s) {
        float4 x = *(float4*)&sA[s * 128 + k0];
        acc[s] += x.x * w0 + x.y * w1 + x.z * w2 + x.w * w3;
      }
    }
#pragma unroll
    for (int s = 0; s < SPB; ++s) sP[wv * 256 + s * 64 + lane] = acc[s];
  }
  __syncthreads();

  // Reduce ctx into sB[s*64+c]
  {
    int o = t;   // 256 outputs = 4 samples x 64 cols
    float v = b2[o & 63] + sP[o] + sP[256 + o] + sP[512 + o] + sP[768 + o];
    sB[o] = v;
  }
  __syncthreads();

  //============ GEMM2: z1 = silu(ctx @ V1[64:,:]) (K=64, col-split 4) ======
  {
    const int c = 64 * wv + lane;
    float acc[SPB];
    float cb = c1[c];
#pragma unroll
    for (int s = 0; s < SPB; ++s) acc[s] = cb;
    const float* wp = V1 + (size_t)64 * 256 + c;
#pragma unroll 4
    for (int m = 0; m < 16; ++m) {      // K=64
      int k0 = 4 * m;
      float w0 = wp[(k0 + 0) * 256];
      float w1 = wp[(k0 + 1) * 256];
      float w2 = wp[(k0 + 2) * 256];
      float w3 = wp[(k0 + 3) * 256];
#pragma unroll
      for (int s = 0; s < SPB; ++s) {
        float4 x = *(float4*)&sB[s * 64 + k0];
        acc[s] += x.x * w0 + x.y * w1 + x.z * w2 + x.w * w3;
      }
    }
#pragma unroll
    for (int s = 0; s < SPB; ++s) sA[s * 256 + c] = siluf(acc[s]);
  }
  __syncthreads();

  //============ GEMM3: z2 = silu(z1 @ V2) (K=256, col-split 4) ============
  {
    const int c = 64 * wv + lane;
    float acc[SPB];
    float cb = c2[c];
#pragma unroll
    for (int s = 0; s < SPB; ++s) acc[s] = cb;
    const float* wp = V2 + c;
#pragma unroll 4
    for (int m = 0; m < 64; ++m) {      // K=256
      int k0 = 4 * m;
      float w0 = wp[(size_t)(k0 + 0) * 256];
      float w1 = wp[(size_t)(k0 + 1) * 256];
      float w2 = wp[(size_t)(k0 + 2) * 256];
      float w3 = wp[(size_t)(k0 + 3) * 256];
#pragma unroll
      for (int s = 0; s < SPB; ++s) {
        float4 x = *(float4*)&sA[s * 256 + k0];
        acc[s] += x.x * w0 + x.y * w1 + x.z * w2 + x.w * w3;
      }
    }
#pragma unroll
    for (int s = 0; s < SPB; ++s) sB[s * 256 + c] = siluf(acc[s]);
  }
  __syncthreads();

  //============ GEMM4 partial: bl = z2 @ V3 (K=256, k-split 4) ============
  {
    float acc[SPB] = {};
    const int kb = 64 * wv;
#pragma unroll 4
    for (int m = 0; m < 16; ++m) {
      int k0 = kb + 4 * m;
      float w0 = V3[(k0 + 0) * 64 + lane];
      float w1 = V3[(k0 + 1) * 64 + lane];
      float w2 = V3[(k0 + 2) * 64 + lane];
      float w3 = V3[(k0 + 3) * 64 + lane];
#pragma unroll
      for (int s = 0; s < SPB; ++s) {
        float4 x = *(float4*)&sB[s * 256 + k0];
        acc[s] += x.x * w0 + x.y * w1 + x.z * w2 + x.w * w3;
      }
    }
#pragma unroll
    for (int s = 0; s < SPB; ++s) sP[wv * 256 + s * 64 + lane] = acc[s];
  }
  __syncthreads();

  //============ Phase B: beta top-5 + PL (one sample per wave) ============
  {
    int b = bbase + wv;
    float blv = c3[lane] + sP[wv * 64 + lane] + sP[256 + wv * 64 + lane]
              + sP[512 + wv * 64 + lane] + sP[768 + wv * 64 + lane];
    float eb = expf(blv);
    float Zb = waveSum(eb);
    float u = ub[(size_t)b * 64 + lane];
    float g = -logf(-logf(fmaxf(u, 1e-10f)));
    float vcur = blv + g;
    float sel_e[5];
#pragma unroll
    for (int r = 0; r < 5; ++r) {
      float bv = vcur; int bi = lane;
#pragma unroll
      for (int off = 32; off; off >>= 1) {
        float ov = __shfl_xor(bv, off, 64);
        int   oi = __shfl_xor(bi, off, 64);
        if (ov > bv || (ov == bv && oi < bi)) { bv = ov; bi = oi; }
      }
      sel_e[r] = __shfl(eb, bi, 64);
      if (lane == bi) vcur = -INFINITY;
    }
    float isSel = (vcur == -INFINITY) ? 1.0f : 0.0f;
    out[(size_t)b * 128 + 64 + lane] = isSel;            // beta config
    float sl = waveSum(isSel != 0.0f ? blv : 0.0f);
    float S  = waveSum(permSum(sel_e[0], sel_e[1], sel_e[2], sel_e[3],
                               sel_e[4], Zb, lane));
    if (lane == 0)
      out[(size_t)8192 * 128 + b] = sLpA[wv] + sl + logf(S);
  }
}

extern "C" void kernel_launch(void* const* d_in, const int* in_sizes, int n_in,
                              void* d_out, int out_size, void* d_ws, size_t ws_size,
                              hipStream_t stream) {
  const float* ua   = (const float*)d_in[0];
  const float* ub   = (const float*)d_in[1];
  const float* alog = (const float*)d_in[2];
  const float* W1   = (const float*)d_in[3];
  const float* b1   = (const float*)d_in[4];
  const float* W2   = (const float*)d_in[5];
  const float* b2   = (const float*)d_in[6];
  const float* V1   = (const float*)d_in[7];
  const float* c1   = (const float*)d_in[8];
  const float* V2   = (const float*)d_in[9];
  const float* c2   = (const float*)d_in[10];
  const float* V3   = (const float*)d_in[11];
  const float* c3   = (const float*)d_in[12];
  float* out = (float*)d_out;

  pcf_fused<<<dim3(8192 / SPB), dim3(NTH), 0, stream>>>(
      ua, ub, alog, W1, b1, W2, b2, V1, c1, V2, c2, V3, c3, out);
}